// Round 1
// baseline (1456.977 us; speedup 1.0000x reference)
//
#include <hip/hip_runtime.h>

#define NPT    4096
#define NBATCH 16
#define NS     512
#define KSAMP  32
#define MROWS  (NBATCH*NS*KSAMP)   // 262144
#define RC2    0.04f

// ---------------------------------------------------------------------------
// K1: farthest point sampling. One block per batch. xyz in LDS, distances in
// registers (16 pts/thread). Packed u64 (float_bits<<32 | ~idx) argmax gives
// numpy first-index tie-break. One barrier per step (parity double-buffer).
// Distances use _rn intrinsics: bit-exact vs numpy's square-then-sum.
// ---------------------------------------------------------------------------
__global__ __launch_bounds__(256) void fps_kernel(const float* __restrict__ xyz,
                                                  float* __restrict__ out_newxyz,
                                                  float* __restrict__ ws_newxyz)
{
  __shared__ float pts[NPT*3];
  __shared__ unsigned long long red[8];   // two parity quads
  const int t = threadIdx.x;
  const int b = blockIdx.x;
  const float* xb = xyz + (size_t)b * NPT * 3;

  { // coalesced copy to LDS
    const float4* s4 = (const float4*)xb;
    float4* d4 = (float4*)pts;
    for (int i = t; i < NPT*3/4; i += 256) d4[i] = s4[i];
  }
  __syncthreads();

  float px[16], py[16], pz[16], dist[16];
#pragma unroll
  for (int j = 0; j < 16; ++j) {
    int i = t + (j << 8);
    px[j] = pts[i*3+0]; py[j] = pts[i*3+1]; pz[j] = pts[i*3+2];
    dist[j] = 1e10f;
  }

  int far = 0;
  const int lane = t & 63, w = t >> 6;
  for (int s = 0; s < NS; ++s) {
    const float cx = pts[far*3+0], cy = pts[far*3+1], cz = pts[far*3+2];
    if (t == 0) {
      int ob = (b*NS + s)*3;
      out_newxyz[ob+0] = cx; out_newxyz[ob+1] = cy; out_newxyz[ob+2] = cz;
      ws_newxyz[ob+0]  = cx; ws_newxyz[ob+1]  = cy; ws_newxyz[ob+2]  = cz;
    }
    if (s == NS-1) break;

    unsigned long long best = 0ull;
#pragma unroll
    for (int j = 0; j < 16; ++j) {
      float dx = __fsub_rn(px[j], cx);
      float dy = __fsub_rn(py[j], cy);
      float dz = __fsub_rn(pz[j], cz);
      float dd = __fadd_rn(__fadd_rn(__fmul_rn(dx,dx), __fmul_rn(dy,dy)), __fmul_rn(dz,dz));
      float nd = fminf(dist[j], dd);
      dist[j] = nd;
      unsigned long long key = ((unsigned long long)__float_as_uint(nd) << 32)
                             | (unsigned int)(~(unsigned int)(t + (j<<8)));
      if (key > best) best = key;
    }
#pragma unroll
    for (int off = 1; off < 64; off <<= 1) {
      unsigned long long o = __shfl_xor(best, off);
      if (o > best) best = o;
    }
    unsigned long long* rr = &red[(s & 1) * 4];
    if (lane == 0) rr[w] = best;
    __syncthreads();
    unsigned long long g = rr[0];
    if (rr[1] > g) g = rr[1];
    if (rr[2] > g) g = rr[2];
    if (rr[3] > g) g = rr[3];
    far = (int)(~(unsigned int)g);   // low 32 bits were ~idx
  }
}

// ---------------------------------------------------------------------------
// K2: ball query (first-32-by-index within radius, pad with first), gather,
// build feats[262144][6], and accumulate per-block partial moments (6 sums +
// 21 upper-tri products) for analytic layer-0 BN stats. One query per wave.
// Distance formula replicates numpy: ((-2*dot) + |q|^2) + |p|^2, no FMA.
// ---------------------------------------------------------------------------
__global__ __launch_bounds__(256) void ball_kernel(const float* __restrict__ xyz,
                                                   const float* __restrict__ pointsf,
                                                   const float* __restrict__ ws_newxyz,
                                                   float* __restrict__ feats,
                                                   float* __restrict__ mpart)
{
  __shared__ int sel[4][KSAMP];
  __shared__ float momw[4][27];
  const int t = threadIdx.x, lane = t & 63, w = t >> 6;
  const int q = blockIdx.x * 4 + w;         // 0..8191
  const int b = q >> 9;
  const float* xb = xyz     + (size_t)b * NPT * 3;
  const float* pb = pointsf + (size_t)b * NPT * 3;

  const float qx = ws_newxyz[q*3+0], qy = ws_newxyz[q*3+1], qz = ws_newxyz[q*3+2];
  const float q2 = __fadd_rn(__fadd_rn(__fmul_rn(qx,qx), __fmul_rn(qy,qy)), __fmul_rn(qz,qz));

  int count = 0;
  for (int c = 0; c < 64 && count < KSAMP; ++c) {
    int i = (c << 6) + lane;
    float fx = xb[i*3+0], fy = xb[i*3+1], fz = xb[i*3+2];
    float p2 = __fadd_rn(__fadd_rn(__fmul_rn(fx,fx), __fmul_rn(fy,fy)), __fmul_rn(fz,fz));
    float e  = __fadd_rn(__fadd_rn(__fmul_rn(qx,fx), __fmul_rn(qy,fy)), __fmul_rn(qz,fz));
    float d  = __fadd_rn(__fadd_rn(__fmul_rn(-2.0f, e), q2), p2);
    bool keep = (d <= RC2);
    unsigned long long mask = __ballot(keep ? 1 : 0);
    int slot = count + (int)__popcll(mask & ((1ull << lane) - 1ull));
    if (keep && slot < KSAMP) sel[w][slot] = i;
    count += (int)__popcll(mask);
  }
  __syncthreads();

  float f[6];
  const int n = (count < KSAMP) ? count : KSAMP;
  if (lane < KSAMP) {
    int id = (lane < n) ? sel[w][lane] : sel[w][0];
    float gx = xb[id*3+0], gy = xb[id*3+1], gz = xb[id*3+2];
    f[0] = __fsub_rn(gx, qx); f[1] = __fsub_rn(gy, qy); f[2] = __fsub_rn(gz, qz);
    f[3] = pb[id*3+0]; f[4] = pb[id*3+1]; f[5] = pb[id*3+2];
    float* fw = feats + ((size_t)q * KSAMP + lane) * 6;
    fw[0]=f[0]; fw[1]=f[1]; fw[2]=f[2]; fw[3]=f[3]; fw[4]=f[4]; fw[5]=f[5];
  } else {
    f[0]=f[1]=f[2]=f[3]=f[4]=f[5]=0.f;
  }

  // moments: 6 sums + 21 upper-tri products, wave-reduced
  float p[27];
#pragma unroll
  for (int c = 0; c < 6; ++c) p[c] = f[c];
  {
    int m = 6;
#pragma unroll
    for (int c = 0; c < 6; ++c)
#pragma unroll
      for (int d = c; d < 6; ++d) p[m++] = f[c]*f[d];
  }
#pragma unroll
  for (int mm = 0; mm < 27; ++mm) {
    float v = p[mm];
#pragma unroll
    for (int off = 1; off < 64; off <<= 1) v += __shfl_xor(v, off);
    p[mm] = v;
  }
  if (lane == 0) {
#pragma unroll
    for (int mm = 0; mm < 27; ++mm) momw[w][mm] = p[mm];
  }
  __syncthreads();
  if (t < 27)
    mpart[blockIdx.x*27 + t] = momw[0][t] + momw[1][t] + momw[2][t] + momw[3][t];
}

// ---------------------------------------------------------------------------
// R0: reduce moment partials; layer-0 BN stats analytically:
// mean = w·mu + b ; E[h^2] = w^T M2 w + 2b(w·mu) + b^2 ; var = E[h^2]-mean^2.
// ---------------------------------------------------------------------------
__global__ __launch_bounds__(256) void r0_kernel(const float* __restrict__ mpart,
                                                 const float* __restrict__ w0,
                                                 const float* __restrict__ b0,
                                                 const float* __restrict__ g0,
                                                 const float* __restrict__ be0,
                                                 float* __restrict__ sc0,
                                                 float* __restrict__ sh0)
{
  __shared__ double mred[8][27];
  __shared__ double mom[27];
  const int t = threadIdx.x;
  const int m = t & 31, j = t >> 5;
  if (m < 27) {
    double s = 0.0;
    for (int p = j; p < 2048; p += 8) s += (double)mpart[p*27 + m];
    mred[j][m] = s;
  }
  __syncthreads();
  if (t < 27) {
    double s = 0.0;
    for (int jj = 0; jj < 8; ++jj) s += mred[jj][t];
    mom[t] = s / (double)MROWS;
  }
  __syncthreads();
  if (t < 64) {
    double wv[6];
    for (int c = 0; c < 6; ++c) wv[c] = (double)w0[t*6 + c];
    double bb = (double)b0[t];
    double mean = bb;
    for (int c = 0; c < 6; ++c) mean += wv[c] * mom[c];
    double e2 = 0.0;
    int mi = 6;
    for (int c = 0; c < 6; ++c)
      for (int d = c; d < 6; ++d) {
        double coef = (c == d) ? wv[c]*wv[c] : 2.0*wv[c]*wv[d];
        e2 += coef * mom[mi++];
      }
    double Eh2 = e2 + 2.0*bb*(mean - bb) + bb*bb;
    double var = Eh2 - mean*mean;
    float vf = (float)var + 1e-5f;
    float sc = g0[t] / sqrtf(vf);
    sc0[t] = sc;
    sh0[t] = be0[t] - (float)mean * sc;
  }
}

// ---------------------------------------------------------------------------
// shared MLP stage helpers (block = 256 threads, tile = 64 rows)
// ---------------------------------------------------------------------------
__device__ __forceinline__ void fma4(float4 v, float4 w4, float& a) {
  a = fmaf(v.x, w4.x, a); a = fmaf(v.y, w4.y, a);
  a = fmaf(v.z, w4.z, a); a = fmaf(v.w, w4.w, a);
}

__device__ __forceinline__ void stage_x0(const float* __restrict__ feats, int blk, int t,
                                         const float* __restrict__ w0, const float* __restrict__ b0,
                                         const float* __restrict__ sc0, const float* __restrict__ sh0,
                                         float* xf, float* x0)
{
  const float* fsrc = feats + (size_t)blk * (64*6);
  for (int i = t; i < 64*6; i += 256) xf[i] = fsrc[i];
  const int o = t & 63, rq = t >> 6;
  float w0r[6];
#pragma unroll
  for (int c = 0; c < 6; ++c) w0r[c] = w0[o*6 + c];
  const float b0v = b0[o], scv = sc0[o], shv = sh0[o];
  __syncthreads();
#pragma unroll
  for (int jj = 0; jj < 16; ++jj) {
    const int r = rq*16 + jj;
    const float* fr = xf + r*6;
    float a = b0v;
#pragma unroll
    for (int c = 0; c < 6; ++c) a = fmaf(fr[c], w0r[c], a);
    x0[r*64 + o] = fmaxf(fmaf(a, scv, shv), 0.0f);
  }
  __syncthreads();
}

__device__ __forceinline__ void stage_x1(int t,
                                         const float* __restrict__ w1, const float* __restrict__ b1,
                                         const float* __restrict__ sc1, const float* __restrict__ sh1,
                                         const float* x0, float* x1)
{
  const int o = t & 63, rq = t >> 6;
  float4 wr[16];
  const float4* wsrc = (const float4*)(w1 + o*64);
#pragma unroll
  for (int i = 0; i < 16; ++i) wr[i] = wsrc[i];
  const float b1v = b1[o], scv = sc1[o], shv = sh1[o];
#pragma unroll
  for (int jj = 0; jj < 16; jj += 4) {
    const float4* xb = (const float4*)(x0 + (rq*16 + jj)*64);
    float a0=b1v, a1=b1v, a2=b1v, a3=b1v;
#pragma unroll
    for (int k = 0; k < 16; ++k) {
      float4 w4 = wr[k];
      fma4(xb[k],      w4, a0);
      fma4(xb[16+k],   w4, a1);
      fma4(xb[32+k],   w4, a2);
      fma4(xb[48+k],   w4, a3);
    }
    x1[(rq*16+jj+0)*64 + o] = fmaxf(fmaf(a0, scv, shv), 0.0f);
    x1[(rq*16+jj+1)*64 + o] = fmaxf(fmaf(a1, scv, shv), 0.0f);
    x1[(rq*16+jj+2)*64 + o] = fmaxf(fmaf(a2, scv, shv), 0.0f);
    x1[(rq*16+jj+3)*64 + o] = fmaxf(fmaf(a3, scv, shv), 0.0f);
  }
  __syncthreads();
}

// ---------------------------------------------------------------------------
// K4: feats -> h0 -> bn0/relu -> h1 (raw), partial sum/sumsq per channel.
// ---------------------------------------------------------------------------
__global__ __launch_bounds__(256) void mlp_stats1_kernel(const float* __restrict__ feats,
    const float* __restrict__ w0, const float* __restrict__ b0,
    const float* __restrict__ sc0, const float* __restrict__ sh0,
    const float* __restrict__ w1, const float* __restrict__ b1,
    float* __restrict__ s1part, float* __restrict__ q1part)
{
  __shared__ __align__(16) float xf[64*6];
  __shared__ __align__(16) float x0[64*64];
  __shared__ float sred[4][64], qred[4][64];
  const int t = threadIdx.x, blk = blockIdx.x;
  stage_x0(feats, blk, t, w0, b0, sc0, sh0, xf, x0);

  const int o = t & 63, rq = t >> 6;
  float4 wr[16];
  const float4* wsrc = (const float4*)(w1 + o*64);
#pragma unroll
  for (int i = 0; i < 16; ++i) wr[i] = wsrc[i];
  const float b1v = b1[o];
  float ssum = 0.f, qsum = 0.f;
#pragma unroll
  for (int jj = 0; jj < 16; jj += 4) {
    const float4* xb = (const float4*)(x0 + (rq*16 + jj)*64);
    float a0=b1v, a1=b1v, a2=b1v, a3=b1v;
#pragma unroll
    for (int k = 0; k < 16; ++k) {
      float4 w4 = wr[k];
      fma4(xb[k], w4, a0); fma4(xb[16+k], w4, a1);
      fma4(xb[32+k], w4, a2); fma4(xb[48+k], w4, a3);
    }
    ssum += ((a0+a1)+(a2+a3));
    qsum += ((a0*a0+a1*a1)+(a2*a2+a3*a3));
  }
  sred[rq][o] = ssum; qred[rq][o] = qsum;
  __syncthreads();
  if (t < 64) {
    s1part[blk*64 + t] = sred[0][t]+sred[1][t]+sred[2][t]+sred[3][t];
    q1part[blk*64 + t] = qred[0][t]+qred[1][t]+qred[2][t]+qred[3][t];
  }
}

// ---------------------------------------------------------------------------
// R1/R2: reduce partial stats -> scale/shift
// ---------------------------------------------------------------------------
__global__ __launch_bounds__(512) void rstats_kernel(const float* __restrict__ spart,
    const float* __restrict__ qpart, int nblk, int nch,
    const float* __restrict__ gamma, const float* __restrict__ beta,
    float* __restrict__ scale, float* __restrict__ shift)
{
  __shared__ double sred[512], qred[512];
  const int t = threadIdx.x;
  const int ch = t % nch, j = t / nch, njs = 512 / nch;
  double s = 0.0, qq = 0.0;
  for (int p = j; p < nblk; p += njs) {
    s  += (double)spart[p*nch + ch];
    qq += (double)qpart[p*nch + ch];
  }
  sred[t] = s; qred[t] = qq;
  __syncthreads();
  if (t < nch) {
    for (int jj = 1; jj < njs; ++jj) { s += sred[jj*nch + t]; qq += qred[jj*nch + t]; }
    double mean = s / (double)MROWS;
    double var  = qq / (double)MROWS - mean*mean;
    float vf = (float)var + 1e-5f;
    float sc = gamma[t] / sqrtf(vf);
    scale[t] = sc;
    shift[t] = beta[t] - (float)mean * sc;
  }
}

// ---------------------------------------------------------------------------
// K5: feats -> ... -> h2 (raw), partial stats for layer 2.
// ---------------------------------------------------------------------------
__global__ __launch_bounds__(256) void mlp_stats2_kernel(const float* __restrict__ feats,
    const float* __restrict__ w0, const float* __restrict__ b0,
    const float* __restrict__ sc0, const float* __restrict__ sh0,
    const float* __restrict__ w1, const float* __restrict__ b1,
    const float* __restrict__ sc1, const float* __restrict__ sh1,
    const float* __restrict__ w2, const float* __restrict__ b2,
    float* __restrict__ s2part, float* __restrict__ q2part)
{
  __shared__ __align__(16) float xf[64*6];
  __shared__ __align__(16) float x0[64*64];
  __shared__ __align__(16) float x1[64*64];
  __shared__ float s2red[2][128], q2red[2][128];
  const int t = threadIdx.x, blk = blockIdx.x;
  stage_x0(feats, blk, t, w0, b0, sc0, sh0, xf, x0);
  stage_x1(t, w1, b1, sc1, sh1, x0, x1);

  const int o2 = t & 127, half = t >> 7;
  float4 wr2[16];
  const float4* w2src = (const float4*)(w2 + o2*64);
#pragma unroll
  for (int i = 0; i < 16; ++i) wr2[i] = w2src[i];
  const float b2v = b2[o2];
  float ssum = 0.f, qsum = 0.f;
#pragma unroll
  for (int jj = 0; jj < 32; jj += 4) {
    const float4* xb = (const float4*)(x1 + (half*32 + jj)*64);
    float a0=b2v, a1=b2v, a2=b2v, a3=b2v;
#pragma unroll
    for (int k = 0; k < 16; ++k) {
      float4 w4 = wr2[k];
      fma4(xb[k], w4, a0); fma4(xb[16+k], w4, a1);
      fma4(xb[32+k], w4, a2); fma4(xb[48+k], w4, a3);
    }
    ssum += ((a0+a1)+(a2+a3));
    qsum += ((a0*a0+a1*a1)+(a2*a2+a3*a3));
  }
  s2red[half][o2] = ssum; q2red[half][o2] = qsum;
  __syncthreads();
  if (t < 128) {
    s2part[blk*128 + t] = s2red[0][t] + s2red[1][t];
    q2part[blk*128 + t] = q2red[0][t] + q2red[1][t];
  }
}

// ---------------------------------------------------------------------------
// K6: full recompute -> bn2/relu -> max over k=32 -> new_points output.
// ---------------------------------------------------------------------------
__global__ __launch_bounds__(256) void mlp_final_kernel(const float* __restrict__ feats,
    const float* __restrict__ w0, const float* __restrict__ b0,
    const float* __restrict__ sc0, const float* __restrict__ sh0,
    const float* __restrict__ w1, const float* __restrict__ b1,
    const float* __restrict__ sc1, const float* __restrict__ sh1,
    const float* __restrict__ w2, const float* __restrict__ b2,
    const float* __restrict__ sc2, const float* __restrict__ sh2,
    float* __restrict__ outp)
{
  __shared__ __align__(16) float xf[64*6];
  __shared__ __align__(16) float x0[64*64];
  __shared__ __align__(16) float x1[64*64];
  const int t = threadIdx.x, blk = blockIdx.x;
  stage_x0(feats, blk, t, w0, b0, sc0, sh0, xf, x0);
  stage_x1(t, w1, b1, sc1, sh1, x0, x1);

  const int o2 = t & 127, half = t >> 7;
  float4 wr2[16];
  const float4* w2src = (const float4*)(w2 + o2*64);
#pragma unroll
  for (int i = 0; i < 16; ++i) wr2[i] = w2src[i];
  const float b2v = b2[o2], scv = sc2[o2], shv = sh2[o2];
  float mx = 0.0f;   // relu floor: max(relu(x)) == max(0, all x)
#pragma unroll
  for (int jj = 0; jj < 32; jj += 4) {
    const float4* xb = (const float4*)(x1 + (half*32 + jj)*64);
    float a0=b2v, a1=b2v, a2=b2v, a3=b2v;
#pragma unroll
    for (int k = 0; k < 16; ++k) {
      float4 w4 = wr2[k];
      fma4(xb[k], w4, a0); fma4(xb[16+k], w4, a1);
      fma4(xb[32+k], w4, a2); fma4(xb[48+k], w4, a3);
    }
    float r0 = fmaf(a0, scv, shv), r1 = fmaf(a1, scv, shv);
    float r2v = fmaf(a2, scv, shv), r3 = fmaf(a3, scv, shv);
    mx = fmaxf(mx, fmaxf(fmaxf(r0, r1), fmaxf(r2v, r3)));
  }
  const int g = blk*2 + half;   // (b*512+s)
  outp[(size_t)g*128 + o2] = mx;
}

// ---------------------------------------------------------------------------
extern "C" void kernel_launch(void* const* d_in, const int* in_sizes, int n_in,
                              void* d_out, int out_size, void* d_ws, size_t ws_size,
                              hipStream_t stream)
{
  const float* xyz     = (const float*)d_in[0];
  const float* pointsf = (const float*)d_in[1];
  const float* w0  = (const float*)d_in[2];
  const float* b0  = (const float*)d_in[3];
  const float* g0  = (const float*)d_in[4];
  const float* be0 = (const float*)d_in[5];
  const float* w1  = (const float*)d_in[6];
  const float* b1  = (const float*)d_in[7];
  const float* g1  = (const float*)d_in[8];
  const float* be1 = (const float*)d_in[9];
  const float* w2  = (const float*)d_in[10];
  const float* b2  = (const float*)d_in[11];
  const float* g2  = (const float*)d_in[12];
  const float* be2 = (const float*)d_in[13];

  float* out       = (float*)d_out;
  float* out_newxyz = out;            // 16*512*3 = 24576
  float* out_newpts = out + 24576;    // 16*512*128

  float* ws = (float*)d_ws;
  float* ws_newxyz = ws;                       // 24576
  float* feats = ws_newxyz + 24576;            // 262144*6 = 1572864
  float* mpart = feats + 1572864;              // 2048*27  = 55296
  float* s1    = mpart + 55296;                // 4096*64
  float* q1    = s1 + 262144;
  float* s2    = q1 + 262144;                  // 4096*128
  float* q2    = s2 + 524288;
  float* sc0   = q2 + 524288;
  float* sh0   = sc0 + 64;
  float* sc1   = sh0 + 64;
  float* sh1   = sc1 + 64;
  float* sc2   = sh1 + 64;
  float* sh2   = sc2 + 128;

  fps_kernel<<<NBATCH, 256, 0, stream>>>(xyz, out_newxyz, ws_newxyz);
  ball_kernel<<<2048, 256, 0, stream>>>(xyz, pointsf, ws_newxyz, feats, mpart);
  r0_kernel<<<1, 256, 0, stream>>>(mpart, w0, b0, g0, be0, sc0, sh0);
  mlp_stats1_kernel<<<4096, 256, 0, stream>>>(feats, w0, b0, sc0, sh0, w1, b1, s1, q1);
  rstats_kernel<<<1, 512, 0, stream>>>(s1, q1, 4096, 64, g1, be1, sc1, sh1);
  mlp_stats2_kernel<<<4096, 256, 0, stream>>>(feats, w0, b0, sc0, sh0, w1, b1, sc1, sh1,
                                              w2, b2, s2, q2);
  rstats_kernel<<<1, 512, 0, stream>>>(s2, q2, 4096, 128, g2, be2, sc2, sh2);
  mlp_final_kernel<<<4096, 256, 0, stream>>>(feats, w0, b0, sc0, sh0, w1, b1, sc1, sh1,
                                             w2, b2, sc2, sh2, out_newpts);
}

// Round 2
// 697.533 us; speedup vs baseline: 2.0888x; 2.0888x over previous
//
#include <hip/hip_runtime.h>

#define NPT    4096
#define NBATCH 16
#define NS     512
#define KSAMP  32
#define MROWS  (NBATCH*NS*KSAMP)   // 262144
#define RC2    0.04f

using bf16x8 = __attribute__((ext_vector_type(8))) short;
using f32x4  = __attribute__((ext_vector_type(4))) float;
#define MFMA16(A,B,C) __builtin_amdgcn_mfma_f32_16x16x32_bf16(A,B,C,0,0,0)

__device__ __forceinline__ unsigned short f2bf(float f) {
  unsigned u = __float_as_uint(f);
  unsigned r = (u + 0x7FFFu + ((u >> 16) & 1u)) >> 16;   // RNE
  return (unsigned short)r;
}
__device__ __forceinline__ float bf2f(unsigned short h) {
  return __uint_as_float(((unsigned)h) << 16);
}

// ---------------------------------------------------------------------------
// K1: farthest point sampling. One block per batch. Distances exact
// (mul/add _rn, numpy order). Argmax key = (dist_bits<<32)|~idx packed as a
// DOUBLE: for non-negative hi words the u64 bit pattern is monotone as f64,
// so v_max_f64 does the whole compare. ~idx gives numpy first-index ties.
// ---------------------------------------------------------------------------
__global__ __launch_bounds__(256) void fps_kernel(const float* __restrict__ xyz,
                                                  float* __restrict__ out_newxyz,
                                                  float* __restrict__ ws_newxyz)
{
  __shared__ float pts[NPT*3];
  __shared__ double red[8];   // two parity quads
  const int t = threadIdx.x;
  const int b = blockIdx.x;
  const float* xb = xyz + (size_t)b * NPT * 3;

  { const float4* s4 = (const float4*)xb;
    float4* d4 = (float4*)pts;
    for (int i = t; i < NPT*3/4; i += 256) d4[i] = s4[i]; }
  __syncthreads();

  float px[16], py[16], pz[16], dist[16];
  unsigned int loc[16];
#pragma unroll
  for (int j = 0; j < 16; ++j) {
    int i = t + (j << 8);
    px[j] = pts[i*3+0]; py[j] = pts[i*3+1]; pz[j] = pts[i*3+2];
    dist[j] = 1e10f;
    loc[j] = ~(unsigned int)i;
  }

  int far = 0;
  const int lane = t & 63, w = t >> 6;
  for (int s = 0; s < NS; ++s) {
    const float cx = pts[far*3+0], cy = pts[far*3+1], cz = pts[far*3+2];
    if (t == 0) {
      int ob = (b*NS + s)*3;
      out_newxyz[ob+0] = cx; out_newxyz[ob+1] = cy; out_newxyz[ob+2] = cz;
      ws_newxyz[ob+0]  = cx; ws_newxyz[ob+1]  = cy; ws_newxyz[ob+2]  = cz;
    }
    if (s == NS-1) break;

    double best = 0.0;
#pragma unroll
    for (int j = 0; j < 16; ++j) {
      float dx = __fsub_rn(px[j], cx);
      float dy = __fsub_rn(py[j], cy);
      float dz = __fsub_rn(pz[j], cz);
      float dd = __fadd_rn(__fadd_rn(__fmul_rn(dx,dx), __fmul_rn(dy,dy)), __fmul_rn(dz,dz));
      float nd = fminf(dist[j], dd);
      dist[j] = nd;
      unsigned long long kk = ((unsigned long long)__float_as_uint(nd) << 32)
                            | (unsigned long long)loc[j];
      best = fmax(best, __longlong_as_double((long long)kk));
    }
#pragma unroll
    for (int off = 1; off < 64; off <<= 1)
      best = fmax(best, __shfl_xor(best, off));
    double* rr = &red[(s & 1) * 4];
    if (lane == 0) rr[w] = best;
    __syncthreads();
    double g = fmax(fmax(rr[0], rr[1]), fmax(rr[2], rr[3]));
    far = (int)(~(unsigned int)(unsigned long long)__double_as_longlong(g));
  }
}

// ---------------------------------------------------------------------------
// K2: ball query (first-32-by-index within radius, pad with first), gather,
// write feats as bf16 [262144][8] (6 real + 2 zero pad), and accumulate
// moments of the ROUNDED values (so analytic BN0 stats match the data the
// MFMA actually consumes). Distance exactly replicates numpy op order.
// ---------------------------------------------------------------------------
__global__ __launch_bounds__(256) void ball_kernel(const float* __restrict__ xyz,
                                                   const float* __restrict__ pointsf,
                                                   const float* __restrict__ ws_newxyz,
                                                   unsigned short* __restrict__ featsbf,
                                                   float* __restrict__ mpart)
{
  __shared__ int sel[4][KSAMP];
  __shared__ float momw[4][27];
  const int t = threadIdx.x, lane = t & 63, w = t >> 6;
  const int q = blockIdx.x * 4 + w;         // 0..8191
  const int b = q >> 9;
  const float* xb = xyz     + (size_t)b * NPT * 3;
  const float* pb = pointsf + (size_t)b * NPT * 3;

  const float qx = ws_newxyz[q*3+0], qy = ws_newxyz[q*3+1], qz = ws_newxyz[q*3+2];
  const float q2 = __fadd_rn(__fadd_rn(__fmul_rn(qx,qx), __fmul_rn(qy,qy)), __fmul_rn(qz,qz));

  int count = 0;
  for (int c = 0; c < 64 && count < KSAMP; ++c) {
    int i = (c << 6) + lane;
    float fx = xb[i*3+0], fy = xb[i*3+1], fz = xb[i*3+2];
    float p2 = __fadd_rn(__fadd_rn(__fmul_rn(fx,fx), __fmul_rn(fy,fy)), __fmul_rn(fz,fz));
    float e  = __fadd_rn(__fadd_rn(__fmul_rn(qx,fx), __fmul_rn(qy,fy)), __fmul_rn(qz,fz));
    float d  = __fadd_rn(__fadd_rn(__fmul_rn(-2.0f, e), q2), p2);
    bool keep = (d <= RC2);
    unsigned long long mask = __ballot(keep ? 1 : 0);
    int slot = count + (int)__popcll(mask & ((1ull << lane) - 1ull));
    if (keep && slot < KSAMP) sel[w][slot] = i;
    count += (int)__popcll(mask);
  }
  __syncthreads();

  float f[6];
  const int n = (count < KSAMP) ? count : KSAMP;
  if (lane < KSAMP) {
    int id = (lane < n) ? sel[w][lane] : sel[w][0];
    float gx = xb[id*3+0], gy = xb[id*3+1], gz = xb[id*3+2];
    unsigned short hb[8];
    hb[0] = f2bf(__fsub_rn(gx, qx));
    hb[1] = f2bf(__fsub_rn(gy, qy));
    hb[2] = f2bf(__fsub_rn(gz, qz));
    hb[3] = f2bf(pb[id*3+0]);
    hb[4] = f2bf(pb[id*3+1]);
    hb[5] = f2bf(pb[id*3+2]);
    hb[6] = 0; hb[7] = 0;
    uint4 pk;
    pk.x = (unsigned)hb[0] | ((unsigned)hb[1] << 16);
    pk.y = (unsigned)hb[2] | ((unsigned)hb[3] << 16);
    pk.z = (unsigned)hb[4] | ((unsigned)hb[5] << 16);
    pk.w = 0;
    ((uint4*)featsbf)[(size_t)q * KSAMP + lane] = pk;
#pragma unroll
    for (int c2 = 0; c2 < 6; ++c2) f[c2] = bf2f(hb[c2]);
  } else {
    f[0]=f[1]=f[2]=f[3]=f[4]=f[5]=0.f;
  }

  float p[27];
#pragma unroll
  for (int c = 0; c < 6; ++c) p[c] = f[c];
  { int m = 6;
#pragma unroll
    for (int c = 0; c < 6; ++c)
#pragma unroll
      for (int d = c; d < 6; ++d) p[m++] = f[c]*f[d]; }
#pragma unroll
  for (int mm = 0; mm < 27; ++mm) {
    float v = p[mm];
#pragma unroll
    for (int off = 1; off < 64; off <<= 1) v += __shfl_xor(v, off);
    p[mm] = v;
  }
  if (lane == 0) {
#pragma unroll
    for (int mm = 0; mm < 27; ++mm) momw[w][mm] = p[mm];
  }
  __syncthreads();
  if (t < 27)
    mpart[blockIdx.x*27 + t] = momw[0][t] + momw[1][t] + momw[2][t] + momw[3][t];
}

// ---------------------------------------------------------------------------
// wconv: weights -> bf16. w0 padded [64][8], w1 [64][64], w2 [128][64].
// ---------------------------------------------------------------------------
__global__ __launch_bounds__(256) void wconv_kernel(const float* __restrict__ w0,
                                                    const float* __restrict__ w1,
                                                    const float* __restrict__ w2,
                                                    unsigned short* __restrict__ wbf0,
                                                    unsigned short* __restrict__ wbf1,
                                                    unsigned short* __restrict__ wbf2)
{
  const int t = threadIdx.x;
  if (t < 64) {
#pragma unroll
    for (int c = 0; c < 8; ++c)
      wbf0[t*8 + c] = (c < 6) ? f2bf(w0[t*6 + c]) : (unsigned short)0;
  }
  for (int i = t; i < 64*64; i += 256) wbf1[i] = f2bf(w1[i]);
  for (int i = t; i < 128*64; i += 256) wbf2[i] = f2bf(w2[i]);
}

// ---------------------------------------------------------------------------
// R0: analytic layer-0 BN from moments of rounded feats + rounded W0.
// Bias cancels when folding, so mean/var are of acc = W·f only.
// ---------------------------------------------------------------------------
__global__ __launch_bounds__(256) void r0_kernel(const float* __restrict__ mpart,
                                                 const unsigned short* __restrict__ wbf0,
                                                 const float* __restrict__ g0,
                                                 const float* __restrict__ be0,
                                                 float* __restrict__ sc0,
                                                 float* __restrict__ sh0)
{
  __shared__ double mred[8][27];
  __shared__ double mom[27];
  const int t = threadIdx.x;
  const int m = t & 31, j = t >> 5;
  if (m < 27) {
    double s = 0.0;
    for (int p = j; p < 2048; p += 8) s += (double)mpart[p*27 + m];
    mred[j][m] = s;
  }
  __syncthreads();
  if (t < 27) {
    double s = 0.0;
    for (int jj = 0; jj < 8; ++jj) s += mred[jj][t];
    mom[t] = s / (double)MROWS;
  }
  __syncthreads();
  if (t < 64) {
    double wv[6];
    for (int c = 0; c < 6; ++c) wv[c] = (double)bf2f(wbf0[t*8 + c]);
    double macc = 0.0;
    for (int c = 0; c < 6; ++c) macc += wv[c] * mom[c];
    double e2 = 0.0;
    int mi = 6;
    for (int c = 0; c < 6; ++c)
      for (int d = c; d < 6; ++d) {
        double coef = (c == d) ? wv[c]*wv[c] : 2.0*wv[c]*wv[d];
        e2 += coef * mom[mi++];
      }
    double var = e2 - macc*macc;
    float sc = g0[t] / sqrtf((float)var + 1e-5f);
    sc0[t] = sc;
    sh0[t] = be0[t] - (float)macc * sc;
  }
}

// ---------------------------------------------------------------------------
// rstats: reduce per-block (sum, sumsq) of raw accumulators -> scale/shift.
// shift = beta - mean_acc*scale (bias cancels exactly).
// ---------------------------------------------------------------------------
__global__ __launch_bounds__(512) void rstats_kernel(const float* __restrict__ spart,
    const float* __restrict__ qpart, int nblk, int nch,
    const float* __restrict__ gamma, const float* __restrict__ beta,
    float* __restrict__ scale, float* __restrict__ shift)
{
  __shared__ double sred[512], qred[512];
  const int t = threadIdx.x;
  const int ch = t % nch, j = t / nch, njs = 512 / nch;
  double s = 0.0, qq = 0.0;
  for (int p = j; p < nblk; p += njs) {
    s  += (double)spart[p*nch + ch];
    qq += (double)qpart[p*nch + ch];
  }
  sred[t] = s; qred[t] = qq;
  __syncthreads();
  if (t < nch) {
    for (int jj = 1; jj < njs; ++jj) { s += sred[jj*nch + t]; qq += qred[jj*nch + t]; }
    double mean = s / (double)MROWS;
    double var  = qq / (double)MROWS - mean*mean;
    float sc = gamma[t] / sqrtf((float)var + 1e-5f);
    scale[t] = sc;
    shift[t] = beta[t] - (float)mean * sc;
  }
}

// ---------------------------------------------------------------------------
// MLP via bf16 MFMA 16x16x32. Block = 256 rows (8 queries), 4 waves, each
// wave owns 64 rows. Activations in LDS bf16, row stride 72 (144 B: 16B
// aligned, uniform 8 dword-accesses/bank => conflict-free-baseline b128s).
// PASS 1: L0,L1 -> stats(L1).  PASS 2: L0,L1,L2 -> stats(L2).
// PASS 3: L0,L1,L2 -> bn2+relu+max over k=32 -> out.
// Frag layouts per cdna_hip_programming.md §3 (A: row=l&15,k=8*(l>>4)+j;
// B: col=l&15, same k; C/D: col=l&15, row=4*(l>>4)+reg  [m89-verified]).
// ---------------------------------------------------------------------------
template<int PASS>
__global__ __launch_bounds__(256) void mlp_kernel(
    const unsigned short* __restrict__ featsbf,
    const unsigned short* __restrict__ wbf0,
    const unsigned short* __restrict__ wbf1,
    const unsigned short* __restrict__ wbf2,
    const float* __restrict__ sc0g, const float* __restrict__ sh0g,
    const float* __restrict__ sc1g, const float* __restrict__ sh1g,
    const float* __restrict__ sc2g, const float* __restrict__ sh2g,
    float* __restrict__ spart, float* __restrict__ qpart,
    float* __restrict__ outp)
{
  __shared__ __align__(16) unsigned short xb[256*72];   // 36864 B
  __shared__ __align__(16) unsigned short wb[128*72];   // 18432 B
  constexpr int SN = (PASS==1) ? 4*64 : (PASS==2 ? 4*128 : 1);
  __shared__ float ssum[SN], sqsum[SN];
  __shared__ float ssc0[64], ssh0[64], ssc1[64], ssh1[64], ssc2[128], ssh2[128];

  // overlays inside wb's upper rows (dead once W2 staging overwrites them)
  unsigned short* wb0 = wb + 64*72;   // [64][8]  bf16, byte off 9216 (16-al)
  unsigned short* xf  = wb + 72*72;   // [256][8] bf16, byte off 10368 (16-al)

  const int t = threadIdx.x, blk = blockIdx.x;
  const int lane = t & 63, w = t >> 6;
  const int lr = lane & 15, lk = lane >> 4;

  // ---- staging ----
  ((uint4*)xf)[t] = ((const uint4*)featsbf)[(size_t)blk*256 + t];
  if (t < 64) ((uint4*)wb0)[t] = ((const uint4*)wbf0)[t];
  { int row = t >> 2, seg = t & 3;   // W1: 64 rows x 128 B
    const uint4* src = (const uint4*)(wbf1 + row*64 + seg*16);
    uint4* dst = (uint4*)(wb + row*72 + seg*16);
    dst[0] = src[0]; dst[1] = src[1]; }
  if (t < 64) { ssc0[t] = sc0g[t]; ssh0[t] = sh0g[t]; }
  if (PASS >= 2 && t < 64) { ssc1[t] = sc1g[t]; ssh1[t] = sh1g[t]; }
  if (PASS == 3 && t < 128) { ssc2[t] = sc2g[t]; ssh2[t] = sh2g[t]; }
  __syncthreads();

  const bf16x8 zb = {0,0,0,0,0,0,0,0};
  const f32x4 fz = {0.f,0.f,0.f,0.f};

  // ---- L0: feats(K=8, 6 real) x W0 -> 64 ch ----
  f32x4 acc[16];
#pragma unroll
  for (int i = 0; i < 16; ++i) acc[i] = fz;
  {
    bf16x8 af[4], bw[4];
#pragma unroll
    for (int i = 0; i < 4; ++i) { af[i] = zb; bw[i] = zb; }
    if (lk == 0) {
#pragma unroll
      for (int rt = 0; rt < 4; ++rt) af[rt] = *(const bf16x8*)&xf[(w*64 + rt*16 + lr)*8];
#pragma unroll
      for (int ct = 0; ct < 4; ++ct) bw[ct] = *(const bf16x8*)&wb0[(ct*16 + lr)*8];
    }
#pragma unroll
    for (int rt = 0; rt < 4; ++rt)
#pragma unroll
      for (int ct = 0; ct < 4; ++ct) acc[rt*4+ct] = MFMA16(af[rt], bw[ct], acc[rt*4+ct]);
  }
  // x0 = relu(acc*sc0 + sh0) -> xb bf16
#pragma unroll
  for (int rt = 0; rt < 4; ++rt)
#pragma unroll
    for (int ct = 0; ct < 4; ++ct) {
      const int ch = ct*16 + lr;
      const float sc = ssc0[ch], sh = ssh0[ch];
#pragma unroll
      for (int r = 0; r < 4; ++r) {
        const int row = w*64 + rt*16 + lk*4 + r;
        float v = fmaxf(fmaf(acc[rt*4+ct][r], sc, sh), 0.f);
        xb[row*72 + ch] = f2bf(v);
      }
    }
  __syncthreads();

  // ---- L1: x0(K=64) x W1 -> 64 ch ----
  f32x4 acc1[16];
#pragma unroll
  for (int i = 0; i < 16; ++i) acc1[i] = fz;
#pragma unroll
  for (int k0 = 0; k0 < 64; k0 += 32) {
    bf16x8 af[4], bw[4];
#pragma unroll
    for (int rt = 0; rt < 4; ++rt) af[rt] = *(const bf16x8*)&xb[(w*64 + rt*16 + lr)*72 + k0 + lk*8];
#pragma unroll
    for (int ct = 0; ct < 4; ++ct) bw[ct] = *(const bf16x8*)&wb[(ct*16 + lr)*72 + k0 + lk*8];
#pragma unroll
    for (int rt = 0; rt < 4; ++rt)
#pragma unroll
      for (int ct = 0; ct < 4; ++ct) acc1[rt*4+ct] = MFMA16(af[rt], bw[ct], acc1[rt*4+ct]);
  }

  if (PASS == 1) {
#pragma unroll
    for (int ct = 0; ct < 4; ++ct) {
      float s = 0.f, q = 0.f;
#pragma unroll
      for (int rt = 0; rt < 4; ++rt)
#pragma unroll
        for (int r = 0; r < 4; ++r) { float v = acc1[rt*4+ct][r]; s += v; q = fmaf(v, v, q); }
      s += __shfl_xor(s, 16); s += __shfl_xor(s, 32);
      q += __shfl_xor(q, 16); q += __shfl_xor(q, 32);
      if (lk == 0) { ssum[w*64 + ct*16 + lr] = s; sqsum[w*64 + ct*16 + lr] = q; }
    }
    __syncthreads();
    if (t < 64) {
      float s = ssum[t] + ssum[64+t] + ssum[128+t] + ssum[192+t];
      float q = sqsum[t] + sqsum[64+t] + sqsum[128+t] + sqsum[192+t];
      spart[blk*64 + t] = s; qpart[blk*64 + t] = q;
    }
    return;
  }

  __syncthreads();   // all waves done reading xb(x0) and wb(W1)

  // stage W2 (overwrites wb incl. overlays)
  { int row = t >> 1, seg = t & 1;   // 128 rows x 128 B
    const uint4* src = (const uint4*)(wbf2 + row*64 + seg*32);
    uint4* dst = (uint4*)(wb + row*72 + seg*32);
    dst[0] = src[0]; dst[1] = src[1]; dst[2] = src[2]; dst[3] = src[3]; }
  // x1 = relu(acc1*sc1 + sh1) -> xb bf16
#pragma unroll
  for (int rt = 0; rt < 4; ++rt)
#pragma unroll
    for (int ct = 0; ct < 4; ++ct) {
      const int ch = ct*16 + lr;
      const float sc = ssc1[ch], sh = ssh1[ch];
#pragma unroll
      for (int r = 0; r < 4; ++r) {
        const int row = w*64 + rt*16 + lk*4 + r;
        float v = fmaxf(fmaf(acc1[rt*4+ct][r], sc, sh), 0.f);
        xb[row*72 + ch] = f2bf(v);
      }
    }
  __syncthreads();

  // ---- L2: x1(K=64) x W2 -> 128 ch, in two 64-ch halves ----
#pragma unroll
  for (int half = 0; half < 2; ++half) {
    f32x4 acc2[16];
#pragma unroll
    for (int i = 0; i < 16; ++i) acc2[i] = fz;
#pragma unroll
    for (int k0 = 0; k0 < 64; k0 += 32) {
      bf16x8 af[4], bw[4];
#pragma unroll
      for (int rt = 0; rt < 4; ++rt) af[rt] = *(const bf16x8*)&xb[(w*64 + rt*16 + lr)*72 + k0 + lk*8];
#pragma unroll
      for (int ct = 0; ct < 4; ++ct) bw[ct] = *(const bf16x8*)&wb[((half*4+ct)*16 + lr)*72 + k0 + lk*8];
#pragma unroll
      for (int rt = 0; rt < 4; ++rt)
#pragma unroll
        for (int ct = 0; ct < 4; ++ct) acc2[rt*4+ct] = MFMA16(af[rt], bw[ct], acc2[rt*4+ct]);
    }
    if (PASS == 2) {
#pragma unroll
      for (int ct = 0; ct < 4; ++ct) {
        float s = 0.f, q = 0.f;
#pragma unroll
        for (int rt = 0; rt < 4; ++rt)
#pragma unroll
          for (int r = 0; r < 4; ++r) { float v = acc2[rt*4+ct][r]; s += v; q = fmaf(v, v, q); }
        s += __shfl_xor(s, 16); s += __shfl_xor(s, 32);
        q += __shfl_xor(q, 16); q += __shfl_xor(q, 32);
        const int ch = (half*4+ct)*16 + lr;
        if (lk == 0) { ssum[w*128 + ch] = s; sqsum[w*128 + ch] = q; }
      }
    } else {
#pragma unroll
      for (int ct = 0; ct < 4; ++ct) {
        const int ch = (half*4+ct)*16 + lr;
        const float sc = ssc2[ch], sh = ssh2[ch];
        float ma = 0.f, mb = 0.f;   // relu floor
#pragma unroll
        for (int r = 0; r < 4; ++r) {
          ma = fmaxf(ma, fmaf(acc2[0*4+ct][r], sc, sh));
          ma = fmaxf(ma, fmaf(acc2[1*4+ct][r], sc, sh));
          mb = fmaxf(mb, fmaf(acc2[2*4+ct][r], sc, sh));
          mb = fmaxf(mb, fmaf(acc2[3*4+ct][r], sc, sh));
        }
        ma = fmaxf(ma, __shfl_xor(ma, 16)); ma = fmaxf(ma, __shfl_xor(ma, 32));
        mb = fmaxf(mb, __shfl_xor(mb, 16)); mb = fmaxf(mb, __shfl_xor(mb, 32));
        if (lk == 0) {
          const int q0 = blk*8 + w*2;
          outp[(size_t)q0*128 + ch]     = ma;
          outp[(size_t)(q0+1)*128 + ch] = mb;
        }
      }
    }
  }
  if (PASS == 2) {
    __syncthreads();
    if (t < 128) {
      float s = ssum[t] + ssum[128+t] + ssum[256+t] + ssum[384+t];
      float q = sqsum[t] + sqsum[128+t] + sqsum[256+t] + sqsum[384+t];
      spart[blk*128 + t] = s; qpart[blk*128 + t] = q;
    }
  }
}

// ---------------------------------------------------------------------------
extern "C" void kernel_launch(void* const* d_in, const int* in_sizes, int n_in,
                              void* d_out, int out_size, void* d_ws, size_t ws_size,
                              hipStream_t stream)
{
  const float* xyz     = (const float*)d_in[0];
  const float* pointsf = (const float*)d_in[1];
  const float* w0  = (const float*)d_in[2];
  const float* g0  = (const float*)d_in[4];
  const float* be0 = (const float*)d_in[5];
  const float* w1  = (const float*)d_in[6];
  const float* g1  = (const float*)d_in[8];
  const float* be1 = (const float*)d_in[9];
  const float* w2  = (const float*)d_in[10];
  const float* g2  = (const float*)d_in[12];
  const float* be2 = (const float*)d_in[13];

  float* out        = (float*)d_out;
  float* out_newxyz = out;            // 16*512*3
  float* out_newpts = out + 24576;    // 16*512*128

  float* ws = (float*)d_ws;
  float* ws_newxyz = ws;                                        // 24576
  unsigned short* featsbf = (unsigned short*)(ws + 24576);      // 262144*8 u16
  float* mpart = ws + 1073152;                                  // 2048*27
  float* s1    = ws + 1128448;                                  // 1024*64
  float* q1    = ws + 1193984;                                  // 1024*64
  float* s2    = ws + 1259520;                                  // 1024*128
  float* q2    = ws + 1390592;                                  // 1024*128
  float* sc0   = ws + 1521664;
  float* sh0   = sc0 + 64;
  float* sc1   = sh0 + 64;
  float* sh1   = sc1 + 64;
  float* sc2   = sh1 + 64;
  float* sh2   = sc2 + 128;                                     // +128 -> 1522176
  unsigned short* wbf0 = (unsigned short*)(ws + 1522176);       // 512 u16
  unsigned short* wbf1 = (unsigned short*)(ws + 1522432);       // 4096 u16
  unsigned short* wbf2 = (unsigned short*)(ws + 1524480);       // 8192 u16

  fps_kernel<<<NBATCH, 256, 0, stream>>>(xyz, out_newxyz, ws_newxyz);
  wconv_kernel<<<1, 256, 0, stream>>>(w0, w1, w2, wbf0, wbf1, wbf2);
  ball_kernel<<<2048, 256, 0, stream>>>(xyz, pointsf, ws_newxyz, featsbf, mpart);
  r0_kernel<<<1, 256, 0, stream>>>(mpart, wbf0, g0, be0, sc0, sh0);
  mlp_kernel<1><<<1024, 256, 0, stream>>>(featsbf, wbf0, wbf1, wbf2,
      sc0, sh0, nullptr, nullptr, nullptr, nullptr, s1, q1, nullptr);
  rstats_kernel<<<1, 512, 0, stream>>>(s1, q1, 1024, 64, g1, be1, sc1, sh1);
  mlp_kernel<2><<<1024, 256, 0, stream>>>(featsbf, wbf0, wbf1, wbf2,
      sc0, sh0, sc1, sh1, nullptr, nullptr, s2, q2, nullptr);
  rstats_kernel<<<1, 512, 0, stream>>>(s2, q2, 1024, 128, g2, be2, sc2, sh2);
  mlp_kernel<3><<<1024, 256, 0, stream>>>(featsbf, wbf0, wbf1, wbf2,
      sc0, sh0, sc1, sh1, sc2, sh2, nullptr, nullptr, out_newpts);
}

// Round 3
// 661.844 us; speedup vs baseline: 2.2014x; 1.0539x over previous
//
#include <hip/hip_runtime.h>

#define NPT    4096
#define NBATCH 16
#define NS     512
#define KSAMP  32
#define MROWS  (NBATCH*NS*KSAMP)   // 262144
#define RC2    0.04f

using bf16x8 = __attribute__((ext_vector_type(8))) short;
using f32x4  = __attribute__((ext_vector_type(4))) float;
using f32x2  = __attribute__((ext_vector_type(2))) float;
#define MFMA16(A,B,C) __builtin_amdgcn_mfma_f32_16x16x32_bf16(A,B,C,0,0,0)

__device__ __forceinline__ unsigned short f2bf(float f) {
  unsigned u = __float_as_uint(f);
  unsigned r = (u + 0x7FFFu + ((u >> 16) & 1u)) >> 16;   // RNE
  return (unsigned short)r;
}
__device__ __forceinline__ float bf2f(unsigned short h) {
  return __uint_as_float(((unsigned)h) << 16);
}

// f64-keyed max with DPP source (key hi-word = dist bits >= 0 so u64 order ==
// f64 order). old=0, bound_ctrl=1: disabled/missing lanes contribute 0 (=id).
template<int CTRL>
__device__ __forceinline__ double dpp_max(double v) {
  long long x = __double_as_longlong(v);
  int lo = __builtin_amdgcn_update_dpp(0, (int)(x & 0xFFFFFFFFll), CTRL, 0xf, 0xf, true);
  int hi = __builtin_amdgcn_update_dpp(0, (int)(x >> 32),          CTRL, 0xf, 0xf, true);
  return fmax(v, __hiloint2double(hi, lo));
}

// ---------------------------------------------------------------------------
// K1: farthest point sampling. One block per batch, 4 waves, 16 pts/thread
// held as 8 float2 pairs (v_pk_* eligible). Per step:
//   compute (contract-off, numpy-exact) -> DPP wave reduce (row_shr/bcast)
//   -> lane63 ds_max_u64 into rotating LDS slot -> barrier -> read -> far.
// Centroids accumulate in LDS; ONE batched global write at the end (avoids
// the per-step vmcnt(0) drain that __syncthreads forces after global stores).
// ---------------------------------------------------------------------------
__global__ __launch_bounds__(256) void fps_kernel(const float* __restrict__ xyz,
                                                  float* __restrict__ out_newxyz,
                                                  float* __restrict__ ws_newxyz)
{
  __shared__ float pts[NPT*3];
  __shared__ float cent[NS*3];
  __shared__ unsigned long long red[4];
  const int t = threadIdx.x;
  const int b = blockIdx.x;
  const float* xb = xyz + (size_t)b * NPT * 3;

  { const float4* s4 = (const float4*)xb;
    float4* d4 = (float4*)pts;
    for (int i = t; i < NPT*3/4; i += 256) d4[i] = s4[i]; }
  if (t < 4) red[t] = 0ull;
  __syncthreads();

  f32x2 px[8], py[8], pz[8], dist[8];
  unsigned int loc0[8], loc1[8];
#pragma unroll
  for (int j = 0; j < 8; ++j) {
    int i0 = t + (2*j)   * 256;
    int i1 = t + (2*j+1) * 256;
    px[j] = f32x2{pts[i0*3+0], pts[i1*3+0]};
    py[j] = f32x2{pts[i0*3+1], pts[i1*3+1]};
    pz[j] = f32x2{pts[i0*3+2], pts[i1*3+2]};
    dist[j] = f32x2{1e10f, 1e10f};
    loc0[j] = ~(unsigned)i0;
    loc1[j] = ~(unsigned)i1;
  }

  int far = 0;
  for (int s = 0; s < NS; ++s) {
    const float cx = pts[far*3+0], cy = pts[far*3+1], cz = pts[far*3+2];
    if (t == 0) { cent[s*3+0] = cx; cent[s*3+1] = cy; cent[s*3+2] = cz; }
    if (s == NS-1) break;

    double best = 0.0;
    {
#pragma clang fp contract(off)
      const f32x2 vcx = {cx, cx}, vcy = {cy, cy}, vcz = {cz, cz};
#pragma unroll
      for (int j = 0; j < 8; ++j) {
        f32x2 dx = px[j] - vcx;
        f32x2 dy = py[j] - vcy;
        f32x2 dz = pz[j] - vcz;
        f32x2 dd = dx*dx + dy*dy + dz*dz;      // contract(off): rn per element
        f32x2 nd;
        nd.x = fminf(dist[j].x, dd.x);
        nd.y = fminf(dist[j].y, dd.y);
        dist[j] = nd;
        unsigned long long k0 = ((unsigned long long)__float_as_uint(nd.x) << 32)
                              | (unsigned long long)loc0[j];
        unsigned long long k1 = ((unsigned long long)__float_as_uint(nd.y) << 32)
                              | (unsigned long long)loc1[j];
        best = fmax(best, __longlong_as_double((long long)k0));
        best = fmax(best, __longlong_as_double((long long)k1));
      }
    }
    // wave64 reduce: lanes' max lands in lane 63
    best = dpp_max<0x111>(best);   // row_shr:1
    best = dpp_max<0x112>(best);   // row_shr:2
    best = dpp_max<0x114>(best);   // row_shr:4
    best = dpp_max<0x118>(best);   // row_shr:8
    best = dpp_max<0x142>(best);   // row_bcast:15
    best = dpp_max<0x143>(best);   // row_bcast:31

    if (t == 0) red[(s+2)&3] = 0ull;           // rotate-reset (2 barriers away)
    if ((t & 63) == 63)
      atomicMax(&red[s&3], (unsigned long long)__double_as_longlong(best));
    __syncthreads();
    far = (int)(~(unsigned)red[s&3]);
  }
  __syncthreads();
  for (int i = t; i < NS*3; i += 256) {
    float v = cent[i];
    out_newxyz[(size_t)b*NS*3 + i] = v;
    ws_newxyz[(size_t)b*NS*3 + i]  = v;
  }
}

// ---------------------------------------------------------------------------
// K2: ball query (first-32-by-index within radius, pad with first), gather,
// write feats as bf16 [262144][8] (6 real + 2 zero pad), and accumulate
// moments of the ROUNDED values (so analytic BN0 stats match the data the
// MFMA actually consumes). Distance exactly replicates numpy op order.
// ---------------------------------------------------------------------------
__global__ __launch_bounds__(256) void ball_kernel(const float* __restrict__ xyz,
                                                   const float* __restrict__ pointsf,
                                                   const float* __restrict__ ws_newxyz,
                                                   unsigned short* __restrict__ featsbf,
                                                   float* __restrict__ mpart)
{
  __shared__ int sel[4][KSAMP];
  __shared__ float momw[4][27];
  const int t = threadIdx.x, lane = t & 63, w = t >> 6;
  const int q = blockIdx.x * 4 + w;         // 0..8191
  const int b = q >> 9;
  const float* xb = xyz     + (size_t)b * NPT * 3;
  const float* pb = pointsf + (size_t)b * NPT * 3;

  const float qx = ws_newxyz[q*3+0], qy = ws_newxyz[q*3+1], qz = ws_newxyz[q*3+2];
  const float q2 = __fadd_rn(__fadd_rn(__fmul_rn(qx,qx), __fmul_rn(qy,qy)), __fmul_rn(qz,qz));

  int count = 0;
  for (int c = 0; c < 64 && count < KSAMP; ++c) {
    int i = (c << 6) + lane;
    float fx = xb[i*3+0], fy = xb[i*3+1], fz = xb[i*3+2];
    float p2 = __fadd_rn(__fadd_rn(__fmul_rn(fx,fx), __fmul_rn(fy,fy)), __fmul_rn(fz,fz));
    float e  = __fadd_rn(__fadd_rn(__fmul_rn(qx,fx), __fmul_rn(qy,fy)), __fmul_rn(qz,fz));
    float d  = __fadd_rn(__fadd_rn(__fmul_rn(-2.0f, e), q2), p2);
    bool keep = (d <= RC2);
    unsigned long long mask = __ballot(keep ? 1 : 0);
    int slot = count + (int)__popcll(mask & ((1ull << lane) - 1ull));
    if (keep && slot < KSAMP) sel[w][slot] = i;
    count += (int)__popcll(mask);
  }
  __syncthreads();

  float f[6];
  const int n = (count < KSAMP) ? count : KSAMP;
  if (lane < KSAMP) {
    int id = (lane < n) ? sel[w][lane] : sel[w][0];
    float gx = xb[id*3+0], gy = xb[id*3+1], gz = xb[id*3+2];
    unsigned short hb[8];
    hb[0] = f2bf(__fsub_rn(gx, qx));
    hb[1] = f2bf(__fsub_rn(gy, qy));
    hb[2] = f2bf(__fsub_rn(gz, qz));
    hb[3] = f2bf(pb[id*3+0]);
    hb[4] = f2bf(pb[id*3+1]);
    hb[5] = f2bf(pb[id*3+2]);
    hb[6] = 0; hb[7] = 0;
    uint4 pk;
    pk.x = (unsigned)hb[0] | ((unsigned)hb[1] << 16);
    pk.y = (unsigned)hb[2] | ((unsigned)hb[3] << 16);
    pk.z = (unsigned)hb[4] | ((unsigned)hb[5] << 16);
    pk.w = 0;
    ((uint4*)featsbf)[(size_t)q * KSAMP + lane] = pk;
#pragma unroll
    for (int c2 = 0; c2 < 6; ++c2) f[c2] = bf2f(hb[c2]);
  } else {
    f[0]=f[1]=f[2]=f[3]=f[4]=f[5]=0.f;
  }

  float p[27];
#pragma unroll
  for (int c = 0; c < 6; ++c) p[c] = f[c];
  { int m = 6;
#pragma unroll
    for (int c = 0; c < 6; ++c)
#pragma unroll
      for (int d = c; d < 6; ++d) p[m++] = f[c]*f[d]; }
#pragma unroll
  for (int mm = 0; mm < 27; ++mm) {
    float v = p[mm];
#pragma unroll
    for (int off = 1; off < 64; off <<= 1) v += __shfl_xor(v, off);
    p[mm] = v;
  }
  if (lane == 0) {
#pragma unroll
    for (int mm = 0; mm < 27; ++mm) momw[w][mm] = p[mm];
  }
  __syncthreads();
  if (t < 27)
    mpart[blockIdx.x*27 + t] = momw[0][t] + momw[1][t] + momw[2][t] + momw[3][t];
}

// ---------------------------------------------------------------------------
// wconv: weights -> bf16. w0 padded [64][8], w1 [64][64], w2 [128][64].
// ---------------------------------------------------------------------------
__global__ __launch_bounds__(256) void wconv_kernel(const float* __restrict__ w0,
                                                    const float* __restrict__ w1,
                                                    const float* __restrict__ w2,
                                                    unsigned short* __restrict__ wbf0,
                                                    unsigned short* __restrict__ wbf1,
                                                    unsigned short* __restrict__ wbf2)
{
  const int t = threadIdx.x;
  if (t < 64) {
#pragma unroll
    for (int c = 0; c < 8; ++c)
      wbf0[t*8 + c] = (c < 6) ? f2bf(w0[t*6 + c]) : (unsigned short)0;
  }
  for (int i = t; i < 64*64; i += 256) wbf1[i] = f2bf(w1[i]);
  for (int i = t; i < 128*64; i += 256) wbf2[i] = f2bf(w2[i]);
}

// ---------------------------------------------------------------------------
// R0: analytic layer-0 BN from moments of rounded feats + rounded W0.
// Bias cancels when folding, so mean/var are of acc = W·f only.
// ---------------------------------------------------------------------------
__global__ __launch_bounds__(256) void r0_kernel(const float* __restrict__ mpart,
                                                 const unsigned short* __restrict__ wbf0,
                                                 const float* __restrict__ g0,
                                                 const float* __restrict__ be0,
                                                 float* __restrict__ sc0,
                                                 float* __restrict__ sh0)
{
  __shared__ double mred[8][27];
  __shared__ double mom[27];
  const int t = threadIdx.x;
  const int m = t & 31, j = t >> 5;
  if (m < 27) {
    double s = 0.0;
    for (int p = j; p < 2048; p += 8) s += (double)mpart[p*27 + m];
    mred[j][m] = s;
  }
  __syncthreads();
  if (t < 27) {
    double s = 0.0;
    for (int jj = 0; jj < 8; ++jj) s += mred[jj][t];
    mom[t] = s / (double)MROWS;
  }
  __syncthreads();
  if (t < 64) {
    double wv[6];
    for (int c = 0; c < 6; ++c) wv[c] = (double)bf2f(wbf0[t*8 + c]);
    double macc = 0.0;
    for (int c = 0; c < 6; ++c) macc += wv[c] * mom[c];
    double e2 = 0.0;
    int mi = 6;
    for (int c = 0; c < 6; ++c)
      for (int d = c; d < 6; ++d) {
        double coef = (c == d) ? wv[c]*wv[c] : 2.0*wv[c]*wv[d];
        e2 += coef * mom[mi++];
      }
    double var = e2 - macc*macc;
    float sc = g0[t] / sqrtf((float)var + 1e-5f);
    sc0[t] = sc;
    sh0[t] = be0[t] - (float)macc * sc;
  }
}

// ---------------------------------------------------------------------------
// rstats: reduce per-block (sum, sumsq) of raw accumulators -> scale/shift.
// shift = beta - mean_acc*scale (bias cancels exactly).
// ---------------------------------------------------------------------------
__global__ __launch_bounds__(512) void rstats_kernel(const float* __restrict__ spart,
    const float* __restrict__ qpart, int nblk, int nch,
    const float* __restrict__ gamma, const float* __restrict__ beta,
    float* __restrict__ scale, float* __restrict__ shift)
{
  __shared__ double sred[512], qred[512];
  const int t = threadIdx.x;
  const int ch = t % nch, j = t / nch, njs = 512 / nch;
  double s = 0.0, qq = 0.0;
  for (int p = j; p < nblk; p += njs) {
    s  += (double)spart[p*nch + ch];
    qq += (double)qpart[p*nch + ch];
  }
  sred[t] = s; qred[t] = qq;
  __syncthreads();
  if (t < nch) {
    for (int jj = 1; jj < njs; ++jj) { s += sred[jj*nch + t]; qq += qred[jj*nch + t]; }
    double mean = s / (double)MROWS;
    double var  = qq / (double)MROWS - mean*mean;
    float sc = gamma[t] / sqrtf((float)var + 1e-5f);
    scale[t] = sc;
    shift[t] = beta[t] - (float)mean * sc;
  }
}

// ---------------------------------------------------------------------------
// MLP via bf16 MFMA 16x16x32. Block = 256 rows (8 queries), 4 waves, each
// wave owns 64 rows. Activations in LDS bf16, row stride 72.
// PASS 1: L0,L1 -> stats(L1).  PASS 2: L0,L1,L2 -> stats(L2).
// PASS 3: L0,L1,L2 -> bn2+relu+max over k=32 -> out.
// ---------------------------------------------------------------------------
template<int PASS>
__global__ __launch_bounds__(256) void mlp_kernel(
    const unsigned short* __restrict__ featsbf,
    const unsigned short* __restrict__ wbf0,
    const unsigned short* __restrict__ wbf1,
    const unsigned short* __restrict__ wbf2,
    const float* __restrict__ sc0g, const float* __restrict__ sh0g,
    const float* __restrict__ sc1g, const float* __restrict__ sh1g,
    const float* __restrict__ sc2g, const float* __restrict__ sh2g,
    float* __restrict__ spart, float* __restrict__ qpart,
    float* __restrict__ outp)
{
  __shared__ __align__(16) unsigned short xb[256*72];   // 36864 B
  __shared__ __align__(16) unsigned short wb[128*72];   // 18432 B
  constexpr int SN = (PASS==1) ? 4*64 : (PASS==2 ? 4*128 : 1);
  __shared__ float ssum[SN], sqsum[SN];
  __shared__ float ssc0[64], ssh0[64], ssc1[64], ssh1[64], ssc2[128], ssh2[128];

  unsigned short* wb0 = wb + 64*72;   // [64][8]  bf16 overlay
  unsigned short* xf  = wb + 72*72;   // [256][8] bf16 overlay

  const int t = threadIdx.x, blk = blockIdx.x;
  const int lane = t & 63, w = t >> 6;
  const int lr = lane & 15, lk = lane >> 4;

  ((uint4*)xf)[t] = ((const uint4*)featsbf)[(size_t)blk*256 + t];
  if (t < 64) ((uint4*)wb0)[t] = ((const uint4*)wbf0)[t];
  { int row = t >> 2, seg = t & 3;   // W1: 64 rows x 128 B
    const uint4* src = (const uint4*)(wbf1 + row*64 + seg*16);
    uint4* dst = (uint4*)(wb + row*72 + seg*16);
    dst[0] = src[0]; dst[1] = src[1]; }
  if (t < 64) { ssc0[t] = sc0g[t]; ssh0[t] = sh0g[t]; }
  if (PASS >= 2 && t < 64) { ssc1[t] = sc1g[t]; ssh1[t] = sh1g[t]; }
  if (PASS == 3 && t < 128) { ssc2[t] = sc2g[t]; ssh2[t] = sh2g[t]; }
  __syncthreads();

  const bf16x8 zb = {0,0,0,0,0,0,0,0};
  const f32x4 fz = {0.f,0.f,0.f,0.f};

  // ---- L0 ----
  f32x4 acc[16];
#pragma unroll
  for (int i = 0; i < 16; ++i) acc[i] = fz;
  {
    bf16x8 af[4], bw[4];
#pragma unroll
    for (int i = 0; i < 4; ++i) { af[i] = zb; bw[i] = zb; }
    if (lk == 0) {
#pragma unroll
      for (int rt = 0; rt < 4; ++rt) af[rt] = *(const bf16x8*)&xf[(w*64 + rt*16 + lr)*8];
#pragma unroll
      for (int ct = 0; ct < 4; ++ct) bw[ct] = *(const bf16x8*)&wb0[(ct*16 + lr)*8];
    }
#pragma unroll
    for (int rt = 0; rt < 4; ++rt)
#pragma unroll
      for (int ct = 0; ct < 4; ++ct) acc[rt*4+ct] = MFMA16(af[rt], bw[ct], acc[rt*4+ct]);
  }
#pragma unroll
  for (int rt = 0; rt < 4; ++rt)
#pragma unroll
    for (int ct = 0; ct < 4; ++ct) {
      const int ch = ct*16 + lr;
      const float sc = ssc0[ch], sh = ssh0[ch];
#pragma unroll
      for (int r = 0; r < 4; ++r) {
        const int row = w*64 + rt*16 + lk*4 + r;
        float v = fmaxf(fmaf(acc[rt*4+ct][r], sc, sh), 0.f);
        xb[row*72 + ch] = f2bf(v);
      }
    }
  __syncthreads();

  // ---- L1 ----
  f32x4 acc1[16];
#pragma unroll
  for (int i = 0; i < 16; ++i) acc1[i] = fz;
#pragma unroll
  for (int k0 = 0; k0 < 64; k0 += 32) {
    bf16x8 af[4], bw[4];
#pragma unroll
    for (int rt = 0; rt < 4; ++rt) af[rt] = *(const bf16x8*)&xb[(w*64 + rt*16 + lr)*72 + k0 + lk*8];
#pragma unroll
    for (int ct = 0; ct < 4; ++ct) bw[ct] = *(const bf16x8*)&wb[(ct*16 + lr)*72 + k0 + lk*8];
#pragma unroll
    for (int rt = 0; rt < 4; ++rt)
#pragma unroll
      for (int ct = 0; ct < 4; ++ct) acc1[rt*4+ct] = MFMA16(af[rt], bw[ct], acc1[rt*4+ct]);
  }

  if (PASS == 1) {
#pragma unroll
    for (int ct = 0; ct < 4; ++ct) {
      float s = 0.f, q = 0.f;
#pragma unroll
      for (int rt = 0; rt < 4; ++rt)
#pragma unroll
        for (int r = 0; r < 4; ++r) { float v = acc1[rt*4+ct][r]; s += v; q = fmaf(v, v, q); }
      s += __shfl_xor(s, 16); s += __shfl_xor(s, 32);
      q += __shfl_xor(q, 16); q += __shfl_xor(q, 32);
      if (lk == 0) { ssum[w*64 + ct*16 + lr] = s; sqsum[w*64 + ct*16 + lr] = q; }
    }
    __syncthreads();
    if (t < 64) {
      float s = ssum[t] + ssum[64+t] + ssum[128+t] + ssum[192+t];
      float q = sqsum[t] + sqsum[64+t] + sqsum[128+t] + sqsum[192+t];
      spart[blk*64 + t] = s; qpart[blk*64 + t] = q;
    }
    return;
  }

  __syncthreads();

  { int row = t >> 1, seg = t & 1;   // W2: 128 rows x 128 B
    const uint4* src = (const uint4*)(wbf2 + row*64 + seg*32);
    uint4* dst = (uint4*)(wb + row*72 + seg*32);
    dst[0] = src[0]; dst[1] = src[1]; dst[2] = src[2]; dst[3] = src[3]; }
#pragma unroll
  for (int rt = 0; rt < 4; ++rt)
#pragma unroll
    for (int ct = 0; ct < 4; ++ct) {
      const int ch = ct*16 + lr;
      const float sc = ssc1[ch], sh = ssh1[ch];
#pragma unroll
      for (int r = 0; r < 4; ++r) {
        const int row = w*64 + rt*16 + lk*4 + r;
        float v = fmaxf(fmaf(acc1[rt*4+ct][r], sc, sh), 0.f);
        xb[row*72 + ch] = f2bf(v);
      }
    }
  __syncthreads();

  // ---- L2 ----
#pragma unroll
  for (int half = 0; half < 2; ++half) {
    f32x4 acc2[16];
#pragma unroll
    for (int i = 0; i < 16; ++i) acc2[i] = fz;
#pragma unroll
    for (int k0 = 0; k0 < 64; k0 += 32) {
      bf16x8 af[4], bw[4];
#pragma unroll
      for (int rt = 0; rt < 4; ++rt) af[rt] = *(const bf16x8*)&xb[(w*64 + rt*16 + lr)*72 + k0 + lk*8];
#pragma unroll
      for (int ct = 0; ct < 4; ++ct) bw[ct] = *(const bf16x8*)&wb[((half*4+ct)*16 + lr)*72 + k0 + lk*8];
#pragma unroll
      for (int rt = 0; rt < 4; ++rt)
#pragma unroll
        for (int ct = 0; ct < 4; ++ct) acc2[rt*4+ct] = MFMA16(af[rt], bw[ct], acc2[rt*4+ct]);
    }
    if (PASS == 2) {
#pragma unroll
      for (int ct = 0; ct < 4; ++ct) {
        float s = 0.f, q = 0.f;
#pragma unroll
        for (int rt = 0; rt < 4; ++rt)
#pragma unroll
          for (int r = 0; r < 4; ++r) { float v = acc2[rt*4+ct][r]; s += v; q = fmaf(v, v, q); }
        s += __shfl_xor(s, 16); s += __shfl_xor(s, 32);
        q += __shfl_xor(q, 16); q += __shfl_xor(q, 32);
        const int ch = (half*4+ct)*16 + lr;
        if (lk == 0) { ssum[w*128 + ch] = s; sqsum[w*128 + ch] = q; }
      }
    } else {
#pragma unroll
      for (int ct = 0; ct < 4; ++ct) {
        const int ch = (half*4+ct)*16 + lr;
        const float sc = ssc2[ch], sh = ssh2[ch];
        float ma = 0.f, mb = 0.f;   // relu floor
#pragma unroll
        for (int r = 0; r < 4; ++r) {
          ma = fmaxf(ma, fmaf(acc2[0*4+ct][r], sc, sh));
          ma = fmaxf(ma, fmaf(acc2[1*4+ct][r], sc, sh));
          mb = fmaxf(mb, fmaf(acc2[2*4+ct][r], sc, sh));
          mb = fmaxf(mb, fmaf(acc2[3*4+ct][r], sc, sh));
        }
        ma = fmaxf(ma, __shfl_xor(ma, 16)); ma = fmaxf(ma, __shfl_xor(ma, 32));
        mb = fmaxf(mb, __shfl_xor(mb, 16)); mb = fmaxf(mb, __shfl_xor(mb, 32));
        if (lk == 0) {
          const int q0 = blk*8 + w*2;
          outp[(size_t)q0*128 + ch]     = ma;
          outp[(size_t)(q0+1)*128 + ch] = mb;
        }
      }
    }
  }
  if (PASS == 2) {
    __syncthreads();
    if (t < 128) {
      float s = ssum[t] + ssum[128+t] + ssum[256+t] + ssum[384+t];
      float q = sqsum[t] + sqsum[128+t] + sqsum[256+t] + sqsum[384+t];
      spart[blk*128 + t] = s; qpart[blk*128 + t] = q;
    }
  }
}

// ---------------------------------------------------------------------------
extern "C" void kernel_launch(void* const* d_in, const int* in_sizes, int n_in,
                              void* d_out, int out_size, void* d_ws, size_t ws_size,
                              hipStream_t stream)
{
  const float* xyz     = (const float*)d_in[0];
  const float* pointsf = (const float*)d_in[1];
  const float* w0  = (const float*)d_in[2];
  const float* g0  = (const float*)d_in[4];
  const float* be0 = (const float*)d_in[5];
  const float* w1  = (const float*)d_in[6];
  const float* g1  = (const float*)d_in[8];
  const float* be1 = (const float*)d_in[9];
  const float* w2  = (const float*)d_in[10];
  const float* g2  = (const float*)d_in[12];
  const float* be2 = (const float*)d_in[13];

  float* out        = (float*)d_out;
  float* out_newxyz = out;            // 16*512*3
  float* out_newpts = out + 24576;    // 16*512*128

  float* ws = (float*)d_ws;
  float* ws_newxyz = ws;                                        // 24576
  unsigned short* featsbf = (unsigned short*)(ws + 24576);      // 262144*8 u16
  float* mpart = ws + 1073152;                                  // 2048*27
  float* s1    = ws + 1128448;                                  // 1024*64
  float* q1    = ws + 1193984;                                  // 1024*64
  float* s2    = ws + 1259520;                                  // 1024*128
  float* q2    = ws + 1390592;                                  // 1024*128
  float* sc0   = ws + 1521664;
  float* sh0   = sc0 + 64;
  float* sc1   = sh0 + 64;
  float* sh1   = sc1 + 64;
  float* sc2   = sh1 + 64;
  float* sh2   = sc2 + 128;
  unsigned short* wbf0 = (unsigned short*)(ws + 1522176);       // 512 u16
  unsigned short* wbf1 = (unsigned short*)(ws + 1522432);       // 4096 u16
  unsigned short* wbf2 = (unsigned short*)(ws + 1524480);       // 8192 u16

  fps_kernel<<<NBATCH, 256, 0, stream>>>(xyz, out_newxyz, ws_newxyz);
  wconv_kernel<<<1, 256, 0, stream>>>(w0, w1, w2, wbf0, wbf1, wbf2);
  ball_kernel<<<2048, 256, 0, stream>>>(xyz, pointsf, ws_newxyz, featsbf, mpart);
  r0_kernel<<<1, 256, 0, stream>>>(mpart, wbf0, g0, be0, sc0, sh0);
  mlp_kernel<1><<<1024, 256, 0, stream>>>(featsbf, wbf0, wbf1, wbf2,
      sc0, sh0, nullptr, nullptr, nullptr, nullptr, s1, q1, nullptr);
  rstats_kernel<<<1, 512, 0, stream>>>(s1, q1, 1024, 64, g1, be1, sc1, sh1);
  mlp_kernel<2><<<1024, 256, 0, stream>>>(featsbf, wbf0, wbf1, wbf2,
      sc0, sh0, sc1, sh1, nullptr, nullptr, s2, q2, nullptr);
  rstats_kernel<<<1, 512, 0, stream>>>(s2, q2, 1024, 128, g2, be2, sc2, sh2);
  mlp_kernel<3><<<1024, 256, 0, stream>>>(featsbf, wbf0, wbf1, wbf2,
      sc0, sh0, sc1, sh1, sc2, sh2, nullptr, nullptr, out_newpts);
}